// Round 9
// baseline (957.277 us; speedup 1.0000x reference)
//
#include <hip/hip_runtime.h>
#include <math.h>

constexpr int D_   = 512;   // d_model
constexpr int H_   = 128;   // extractor hidden
constexpr int P_   = 10;    // n_programs
constexpr int MAXO = 4;
constexpr int BM   = 64;    // tokens per block
constexpr int BK   = 32;    // K chunk (= one MFMA K step)

typedef _Float16 f16;
typedef f16 f16x4 __attribute__((ext_vector_type(4)));
typedef f16 f16x8 __attribute__((ext_vector_type(8)));
typedef float f32x4 __attribute__((ext_vector_type(4)));

__device__ __forceinline__ float gelu_exact(float x) {
    return 0.5f * x * (1.0f + erff(x * 0.70710678118654752f));
}

__device__ __forceinline__ void time_decomp(float t, float& hr, float& mi, float& dy) {
    float days = floorf(t / 1440.0f);
    float rem  = t - days * 1440.0f;
    float hours = floorf(rem / 60.0f);
    float minutes = rem - hours * 60.0f;
    hr = hours; mi = minutes; dy = days;
}

__device__ __forceinline__ void g2l16(const f16* g, f16* l) {
    __builtin_amdgcn_global_load_lds(
        (const __attribute__((address_space(1))) void*)g,
        (__attribute__((address_space(3))) void*)l, 16, 0, 0);
}

// W1 [P][D][H] f32 -> fragment-packed W1S[p][kc][ni][lane][8] f16 hi/lo.
// B-fragment (16x16x32): lane l holds row h=(ni*16+(l&15)), k = kc*32+(l>>4)*8+j
__global__ __launch_bounds__(256) void cvt_w1_kernel(
    const float* __restrict__ W1, f16* __restrict__ hi, f16* __restrict__ lo)
{
    int i = blockIdx.x * 256 + threadIdx.x;      // < P*D*H
    float x = W1[i];
    f16 h = (f16)x;
    f16 L = (f16)(x - (float)h);
    int p   = i / (D_ * H_);
    int rem = i % (D_ * H_);
    int d   = rem / H_;
    int hh  = rem % H_;
    int kc = d >> 5, l4 = (d >> 3) & 3, j = d & 7;
    int ni = hh >> 4, l15 = hh & 15;
    size_t off = ((((size_t)p * 16 + kc) * 8 + ni) * 64 + l4 * 16 + l15) * 8 + j;
    hi[off] = h; lo[off] = L;
}

// Fused: router logits + program_ids-as-float + hidden f32 -> f16 hi/lo split
// (linear [B][D] layout, consumed by the swizzled A-staging).
template <bool WRITE_SPLIT>
__global__ __launch_bounds__(256) void router_cvt_kernel(
    const float* __restrict__ hidden, const float* __restrict__ Wr,
    const float* __restrict__ br, const int* __restrict__ pids,
    float* __restrict__ out_router, float* __restrict__ out_pids,
    f16* __restrict__ hidHi, f16* __restrict__ hidLo, int B)
{
    __shared__ float Wrs[D_ * 12];
    const int tid = threadIdx.x;
    for (int i = tid; i < D_ * P_; i += 256) {
        int k = i / P_;
        int q = i - k * P_;
        Wrs[k * 12 + q] = Wr[i];
    }
    __syncthreads();

    const int lane = tid & 63;
    const int wv   = tid >> 6;
    const int b    = blockIdx.x * 4 + wv;
    const float* hrow = hidden + (size_t)b * D_;

    float acc[P_];
#pragma unroll
    for (int q = 0; q < P_; ++q) acc[q] = 0.0f;

#pragma unroll
    for (int j = 0; j < 8; ++j) {
        int k = j * 64 + lane;
        float hv = hrow[k];
        if (WRITE_SPLIT) {
            f16 hh = (f16)hv;
            hidHi[(size_t)b * D_ + k] = hh;
            hidLo[(size_t)b * D_ + k] = (f16)(hv - (float)hh);
        }
        float wv12[12];
        *reinterpret_cast<float4*>(&wv12[0]) = *reinterpret_cast<const float4*>(&Wrs[k * 12 + 0]);
        *reinterpret_cast<float4*>(&wv12[4]) = *reinterpret_cast<const float4*>(&Wrs[k * 12 + 4]);
        *reinterpret_cast<float2*>(&wv12[8]) = *reinterpret_cast<const float2*>(&Wrs[k * 12 + 8]);
#pragma unroll
        for (int q = 0; q < P_; ++q) acc[q] = fmaf(hv, wv12[q], acc[q]);
    }

#pragma unroll
    for (int off = 1; off < 64; off <<= 1) {
#pragma unroll
        for (int q = 0; q < P_; ++q)
            acc[q] += __shfl_xor(acc[q], off, 64);
    }

    if (lane == 0) {
        float* o = out_router + (size_t)b * P_;
#pragma unroll
        for (int q = 0; q < P_; ++q) o[q] = acc[q] + br[q];
        out_pids[b] = (float)pids[b];
    }
}

template <bool PRECONV>
__global__ __launch_bounds__(256, 4) void extractor_kernel(
    const float* __restrict__ hidden,   // [B, D] f32 (fallback)
    const f16*   __restrict__ hidHi,    // [B, D] (PRECONV)
    const f16*   __restrict__ hidLo,    // [B, D]
    const int*   __restrict__ pids,     // [B]
    const f16*   __restrict__ W1Shi,    // packed [p][kc][ni][64][8]
    const f16*   __restrict__ W1Slo,
    const float* __restrict__ b1,       // [P, H]
    const float* __restrict__ W2,       // [P, H, MAXO]
    const float* __restrict__ b2,       // [P, MAXO]
    float* __restrict__ out_results,    // [B, 3]
    float* __restrict__ out_ops,        // [P, B, MAXO]
    int B)
{
    // LDS: A dbuf only. buf0 {Ah 4K | Al 4K} | buf1 {Ah | Al} = 16K.
    // red [64][16] f32 (4K) aliases buf0 in the epilogue.
    __shared__ __align__(16) char smem[16384];
    float* red = (float*)smem;

    const int bid = blockIdx.x;
    const int ngroups = gridDim.x / P_;
    int g, p;
    if ((ngroups & 7) == 0) {
        // XCD-aware: hw xcd = bid % 8; each XCD gets contiguous (tile, program)
        // groups (program fastest) so a tile's 10 program-blocks share one L2
        // and W1S stays L2-resident.
        const int gpx = ngroups >> 3;
        const int x   = bid & 7;
        const int q   = bid >> 3;
        g = x * gpx + q / P_;
        p = q % P_;
    } else {
        g = bid / P_;
        p = bid % P_;
    }
    const int b0  = g * BM;
    const int tid = threadIdx.x;
    const int l   = tid & 63;
    const int w   = tid >> 6;          // wave = h-strip [w*32, w*32+32)
    const int l15 = l & 15, l4 = l >> 4;

    // ---- swizzle (both-sides involution; proven zero-conflict) ----
    const int sg8 = (((l & 3) ^ ((l >> 3) & 3))) * 8;     // stage-side, f16 units
    const int rd8 = ((l4 ^ ((l15 >> 1) & 3))) * 8;        // read-side, f16 units

    f32x4 acc[4][2];
#pragma unroll
    for (int mi = 0; mi < 4; ++mi)
#pragma unroll
        for (int nn = 0; nn < 2; ++nn) acc[mi][nn] = (f32x4){0.f, 0.f, 0.f, 0.f};

    auto stageA = [&](int kc, char* buf) {
        f16* Ah = (f16*)buf;
        f16* Al = (f16*)(buf + 4096);
        if constexpr (PRECONV) {
            const size_t ga = (size_t)(b0 + w * 16 + (l >> 2)) * D_ + kc * BK + sg8;
            g2l16(hidHi + ga, Ah + w * 512);
            g2l16(hidLo + ga, Al + w * 512);
        } else {
#pragma unroll
            for (int it = 0; it < 2; ++it) {
                int i  = tid + it * 256;        // float4 id, 512 total
                int m  = i >> 3;
                int k4 = (i & 7) * 4;
                int ks = ((k4 >> 3) ^ ((m >> 1) & 3)) * 8 + (k4 & 7);
                f32x4 v = *(const f32x4*)(hidden + (size_t)(b0 + m) * D_ + kc * BK + k4);
                f16x4 vh, vl;
#pragma unroll
                for (int j = 0; j < 4; ++j) {
                    f16 hj = (f16)v[j];
                    vh[j] = hj;
                    vl[j] = (f16)(v[j] - (float)hj);
                }
                *(f16x4*)&Ah[m * BK + ks] = vh;
                *(f16x4*)&Al[m * BK + ks] = vl;
            }
            asm volatile("s_waitcnt lgkmcnt(0)" ::: "memory");
        }
    };

    auto loadB = [&](int kc, f16x8* dh, f16x8* dl) {
        const size_t base = (((size_t)(p * 16 + kc) * 8 + w * 2) * 64 + l) * 8;
        dh[0] = *(const f16x8*)(W1Shi + base);
        dh[1] = *(const f16x8*)(W1Shi + base + 512);
        dl[0] = *(const f16x8*)(W1Slo + base);
        dl[1] = *(const f16x8*)(W1Slo + base + 512);
    };

    auto compute = [&](const char* buf, const f16x8* bh, const f16x8* bl) {
        const f16* Ah = (const f16*)buf;
        const f16* Al = (const f16*)(buf + 4096);
#pragma unroll
        for (int mi = 0; mi < 4; ++mi) {
            int mrow = mi * 16 + l15;
            f16x8 a_h = *(const f16x8*)&Ah[mrow * BK + rd8];
            f16x8 a_l = *(const f16x8*)&Al[mrow * BK + rd8];
#pragma unroll
            for (int nn = 0; nn < 2; ++nn) {
                acc[mi][nn] = __builtin_amdgcn_mfma_f32_16x16x32_f16(a_l, bh[nn], acc[mi][nn], 0, 0, 0);
                acc[mi][nn] = __builtin_amdgcn_mfma_f32_16x16x32_f16(a_h, bl[nn], acc[mi][nn], 0, 0, 0);
                acc[mi][nn] = __builtin_amdgcn_mfma_f32_16x16x32_f16(a_h, bh[nn], acc[mi][nn], 0, 0, 0);
            }
        }
    };

    char* buf0 = smem;
    char* buf1 = smem + 8192;

    f16x8 bAh[2], bAl[2], bBh[2], bBl[2];

    // ---- pipelined K loop: counted vmcnt, 6 VMEM issued per chunk ----
    loadB(0, bAh, bAl);
    stageA(0, buf0);
    asm volatile("s_waitcnt vmcnt(0)" ::: "memory");
    __builtin_amdgcn_s_barrier();
    for (int kc = 0; kc < 16; kc += 2) {
        // even chunk kc: A in buf0, B in bA*
        loadB(kc + 1, bBh, bBl);
        stageA(kc + 1, buf1);
        asm volatile("s_waitcnt vmcnt(6)" ::: "memory");
        __builtin_amdgcn_s_barrier();
        compute(buf0, bAh, bAl);
        __builtin_amdgcn_s_barrier();
        // odd chunk kc+1: A in buf1, B in bB*
        if (kc + 2 < 16) {
            loadB(kc + 2, bAh, bAl);
            stageA(kc + 2, buf0);
            asm volatile("s_waitcnt vmcnt(6)" ::: "memory");
        } else {
            asm volatile("s_waitcnt vmcnt(0)" ::: "memory");
        }
        __builtin_amdgcn_s_barrier();
        compute(buf1, bBh, bBl);
        __builtin_amdgcn_s_barrier();
    }

    // ---- epilogue: bias + exact gelu + GEMM2 partials, butterfly, red combine ----
    float b1v[2];
    f32x4 w4[2];
#pragma unroll
    for (int nn = 0; nn < 2; ++nn) {
        int h = w * 32 + nn * 16 + l15;
        b1v[nn] = b1[p * H_ + h];
        w4[nn]  = *(const f32x4*)(W2 + ((size_t)p * H_ + h) * MAXO);
    }

#pragma unroll
    for (int mi = 0; mi < 4; ++mi) {
        float v[16];
#pragma unroll
        for (int j = 0; j < 16; ++j) v[j] = 0.0f;
#pragma unroll
        for (int nn = 0; nn < 2; ++nn) {
#pragma unroll
            for (int r = 0; r < 4; ++r) {
                float gg = gelu_exact(acc[mi][nn][r] + b1v[nn]);
#pragma unroll
                for (int o = 0; o < 4; ++o) v[r * 4 + o] = fmaf(gg, w4[nn][o], v[r * 4 + o]);
            }
        }
        // transpose-reduce over 16 h-lanes: lane l15 ends holding index l15 = r*4+o
#pragma unroll
        for (int s = 8; s >= 1; s >>= 1) {
            const bool up = (l15 & s) != 0;
#pragma unroll
            for (int j = 0; j < s; ++j) {
                float send = up ? v[j] : v[j + s];
                float keep = up ? v[j + s] : v[j];
                v[j] = keep + __shfl_xor(send, s, 64);
            }
        }
        const int tokl = mi * 16 + l4 * 4 + (l15 >> 2);
        const int o    = l15 & 3;
        red[tokl * 16 + o * 4 + w] = v[0];
    }
    __syncthreads();

    if (tid < BM) {
        const int b = b0 + tid;
        f32x4 q0 = ((const f32x4*)red)[tid * 4 + 0];   // o=0: wn 0..3
        f32x4 q1 = ((const f32x4*)red)[tid * 4 + 1];
        f32x4 q2 = ((const f32x4*)red)[tid * 4 + 2];
        f32x4 q3 = ((const f32x4*)red)[tid * 4 + 3];
        float o0 = q0[0] + q0[1] + q0[2] + q0[3] + b2[p * 4 + 0];
        float o1 = q1[0] + q1[1] + q1[2] + q1[3] + b2[p * 4 + 1];
        float o2 = q2[0] + q2[1] + q2[2] + q2[3] + b2[p * 4 + 2];
        float o3 = q3[0] + q3[1] + q3[2] + q3[3] + b2[p * 4 + 3];
        *reinterpret_cast<float4*>(out_ops + ((size_t)p * B + b) * MAXO) =
            make_float4(o0, o1, o2, o3);

        if (pids[b] == p) {
            float a0 = rintf(o0), a1 = rintf(o1), a2 = rintf(o2), a3 = rintf(o3);
            float r0 = 0.0f, r1 = 0.0f, r2 = 0.0f;
            switch (p) {
                case 0: r0 = a0 + a1; break;
                case 1: r0 = a0 - a1; break;
                case 2: r0 = a0 * a1; break;
                case 3: {
                    float bs = (a1 == 0.0f) ? 1.0f : a1;
                    float m = fmodf(a0, bs);
                    if (m != 0.0f && ((m < 0.0f) != (bs < 0.0f))) m += bs;
                    r0 = m;
                } break;
                case 4: {
                    float bs = (a1 == 0.0f) ? 1.0f : a1;
                    r0 = floorf(a0 / bs);
                } break;
                case 5: { float tt = a0 * 60.0f + a1 + a2 * 60.0f + a3; time_decomp(tt, r0, r1, r2); } break;
                case 6: { float tt = a0 * 60.0f + a1 - (a2 * 60.0f + a3); time_decomp(tt, r0, r1, r2); } break;
                case 7: { float tt = fabsf(a0 * 60.0f + a1 - (a2 * 60.0f + a3)); time_decomp(tt, r0, r1, r2); } break;
                case 8: r0 = (a0 > a1) ? 1.0f : 0.0f; break;
                case 9: r0 = (a0 == a1) ? 1.0f : 0.0f; break;
            }
            size_t ob = (size_t)b * 3;
            out_results[ob + 0] = r0;
            out_results[ob + 1] = r1;
            out_results[ob + 2] = r2;
        }
    }
}

extern "C" void kernel_launch(void* const* d_in, const int* in_sizes, int n_in,
                              void* d_out, int out_size, void* d_ws, size_t ws_size,
                              hipStream_t stream) {
    const float* hidden = (const float*)d_in[0];
    const int*   pids   = (const int*)  d_in[1];
    const float* Wr     = (const float*)d_in[2];
    const float* br     = (const float*)d_in[3];
    const float* W1     = (const float*)d_in[4];
    const float* b1     = (const float*)d_in[5];
    const float* W2     = (const float*)d_in[6];
    const float* b2     = (const float*)d_in[7];

    const int B = in_sizes[1];

    float* out         = (float*)d_out;
    float* out_results = out;                                          // [B,3]
    float* out_router  = out + (size_t)B * 3;                          // [B,10]
    float* out_ops     = out + (size_t)B * 13;                         // [P,B,4]
    float* out_pids    = out + (size_t)B * 13 + (size_t)P_ * B * MAXO; // [B]

    const size_t nW1  = (size_t)P_ * H_ * D_;
    const size_t nHid = (size_t)B * D_;
    const size_t need = (2 * nW1 + 2 * nHid) * sizeof(f16);

    f16* W1Shi = (f16*)d_ws;
    f16* W1Slo = W1Shi + nW1;

    cvt_w1_kernel<<<(int)(nW1 / 256), 256, 0, stream>>>(W1, W1Shi, W1Slo);

    if (ws_size >= need) {
        f16* hidHi = W1Slo + nW1;
        f16* hidLo = hidHi + nHid;
        router_cvt_kernel<true><<<B / 4, 256, 0, stream>>>(
            hidden, Wr, br, pids, out_router, out_pids, hidHi, hidLo, B);
        extractor_kernel<true><<<(B / BM) * P_, 256, 0, stream>>>(
            hidden, hidHi, hidLo, pids, W1Shi, W1Slo, b1, W2, b2,
            out_results, out_ops, B);
    } else {
        router_cvt_kernel<false><<<B / 4, 256, 0, stream>>>(
            hidden, Wr, br, pids, out_router, out_pids, nullptr, nullptr, B);
        extractor_kernel<false><<<(B / BM) * P_, 256, 0, stream>>>(
            hidden, nullptr, nullptr, pids, W1Shi, W1Slo, b1, W2, b2,
            out_results, out_ops, B);
    }
}

// Round 10
// 780.589 us; speedup vs baseline: 1.2264x; 1.2264x over previous
//
#include <hip/hip_runtime.h>
#include <math.h>

constexpr int D_   = 512;   // d_model
constexpr int H_   = 128;   // extractor hidden
constexpr int P_   = 10;    // n_programs
constexpr int MAXO = 4;
constexpr int BM   = 128;   // token tile
constexpr int BK   = 32;    // K chunk (= one MFMA K step)

typedef _Float16 f16;
typedef f16 f16x4 __attribute__((ext_vector_type(4)));
typedef f16 f16x8 __attribute__((ext_vector_type(8)));
typedef float f32x4 __attribute__((ext_vector_type(4)));

__device__ __forceinline__ float gelu_exact(float x) {
    return 0.5f * x * (1.0f + erff(x * 0.70710678118654752f));
}

__device__ __forceinline__ void time_decomp(float t, float& hr, float& mi, float& dy) {
    float days = floorf(t / 1440.0f);
    float rem  = t - days * 1440.0f;
    float hours = floorf(rem / 60.0f);
    float minutes = rem - hours * 60.0f;
    hr = hours; mi = minutes; dy = days;
}

__device__ __forceinline__ void g2l16(const f16* g, f16* l) {
    __builtin_amdgcn_global_load_lds(
        (const __attribute__((address_space(1))) void*)g,
        (__attribute__((address_space(3))) void*)l, 16, 0, 0);
}

// W1 [P][D][H] f32 -> W1T_hi / W1T_lo [P][H][D] f16 (transposed + split)
__global__ __launch_bounds__(256) void cvt_w1_kernel(
    const float* __restrict__ W1, f16* __restrict__ hi, f16* __restrict__ lo)
{
    int i = blockIdx.x * 256 + threadIdx.x;
    float x = W1[i];
    f16 h = (f16)x;
    f16 L = (f16)(x - (float)h);
    int dh = i % (D_ * H_);
    int p  = i / (D_ * H_);
    int d  = dh / H_;
    int hh = dh % H_;
    size_t o = ((size_t)(p * H_ + hh)) * D_ + d;
    hi[o] = h; lo[o] = L;
}

// Fused: router logits + program_ids-as-float + hidden f32 -> f16 hi/lo split.
template <bool WRITE_SPLIT>
__global__ __launch_bounds__(256) void router_cvt_kernel(
    const float* __restrict__ hidden, const float* __restrict__ Wr,
    const float* __restrict__ br, const int* __restrict__ pids,
    float* __restrict__ out_router, float* __restrict__ out_pids,
    f16* __restrict__ hidHi, f16* __restrict__ hidLo, int B)
{
    __shared__ float Wrs[D_ * 12];
    const int tid = threadIdx.x;
    for (int i = tid; i < D_ * P_; i += 256) {
        int k = i / P_;
        int q = i - k * P_;
        Wrs[k * 12 + q] = Wr[i];
    }
    __syncthreads();

    const int lane = tid & 63;
    const int wv   = tid >> 6;
    const int b    = blockIdx.x * 4 + wv;
    const float* hrow = hidden + (size_t)b * D_;

    float acc[P_];
#pragma unroll
    for (int q = 0; q < P_; ++q) acc[q] = 0.0f;

#pragma unroll
    for (int j = 0; j < 8; ++j) {
        int k = j * 64 + lane;
        float hv = hrow[k];
        if (WRITE_SPLIT) {
            f16 hh = (f16)hv;
            hidHi[(size_t)b * D_ + k] = hh;
            hidLo[(size_t)b * D_ + k] = (f16)(hv - (float)hh);
        }
        float wv12[12];
        *reinterpret_cast<float4*>(&wv12[0]) = *reinterpret_cast<const float4*>(&Wrs[k * 12 + 0]);
        *reinterpret_cast<float4*>(&wv12[4]) = *reinterpret_cast<const float4*>(&Wrs[k * 12 + 4]);
        *reinterpret_cast<float2*>(&wv12[8]) = *reinterpret_cast<const float2*>(&Wrs[k * 12 + 8]);
#pragma unroll
        for (int q = 0; q < P_; ++q) acc[q] = fmaf(hv, wv12[q], acc[q]);
    }

#pragma unroll
    for (int off = 1; off < 64; off <<= 1) {
#pragma unroll
        for (int q = 0; q < P_; ++q)
            acc[q] += __shfl_xor(acc[q], off, 64);
    }

    if (lane == 0) {
        float* o = out_router + (size_t)b * P_;
#pragma unroll
        for (int q = 0; q < P_; ++q) o[q] = acc[q] + br[q];
        out_pids[b] = (float)pids[b];
    }
}

template <bool PRECONV>
__global__ __launch_bounds__(256, 2) void extractor_kernel(
    const float* __restrict__ hidden,   // [B, D] f32
    const f16*   __restrict__ hidHi,    // [B, D] (PRECONV only)
    const f16*   __restrict__ hidLo,    // [B, D]
    const int*   __restrict__ pids,     // [B]
    const f16*   __restrict__ W1Thi,    // [P][H][D]
    const f16*   __restrict__ W1Tlo,    // [P][H][D]
    const float* __restrict__ b1,       // [P, H]
    const float* __restrict__ W2,       // [P, H, MAXO]
    const float* __restrict__ b2,       // [P, MAXO]
    float* __restrict__ out_results,    // [B, 3]
    float* __restrict__ out_ops,        // [P, B, MAXO]
    int B)
{
    // LDS: buf0 {Ah,Al,Bh,Bl} 32K | buf1 32K | red 4K | W2s 2K = 71680
    __shared__ __align__(16) char smem[71680];
    float* red = (float*)(smem + 65536);   // [2][128][4]
    float* W2s = (float*)(smem + 69632);   // [128][4]

    const int bid = blockIdx.x;
    const int ngroups = gridDim.x / P_;
    int g, p;
    if ((ngroups & 7) == 0) {
        // XCD-aware: hw xcd = bid % 8; each XCD gets contiguous (tile, program)
        // groups so a tile's 10 program-blocks share one L2.
        const int gpx = ngroups >> 3;
        const int x   = bid & 7;
        const int q   = bid >> 3;
        g = x * gpx + q / P_;
        p = q % P_;
    } else {
        g = bid / P_;
        p = bid % P_;
    }
    const int b0  = g * BM;
    const int tid = threadIdx.x;
    const int l   = tid & 63;
    const int w   = tid >> 6;
    const int wm  = w >> 1, wn = w & 1;
    const int l15 = l & 15, l4 = l >> 4;

    // ---- swizzle (both-sides, involution; rule #21; proven 0-conflict) ----
    const int sg8 = (((l & 3) ^ ((l >> 3) & 3))) * 8;     // stage-side, f16 units
    const int rd8 = ((l4 ^ ((l15 >> 1) & 3))) * 8;        // read-side, f16 units

    if (tid < H_) {
        ((f32x4*)W2s)[tid] = ((const f32x4*)(W2 + (size_t)p * H_ * 4))[tid];
    }

    f32x4 acc[4][4];
#pragma unroll
    for (int mi = 0; mi < 4; ++mi)
#pragma unroll
        for (int ni = 0; ni < 4; ++ni) acc[mi][ni] = (f32x4){0.f, 0.f, 0.f, 0.f};

    const f16* Bhig = W1Thi + (size_t)p * H_ * D_;
    const f16* Blog = W1Tlo + (size_t)p * H_ * D_;

    auto stageB = [&](int kc, char* buf) {
        f16* Bh = (f16*)(buf + 16384);
        f16* Bl = (f16*)(buf + 24576);
#pragma unroll
        for (int t = 0; t < 2; ++t) {
            int h0 = w * 32 + t * 16;                    // wave-uniform LDS base
            size_t go = (size_t)(h0 + (l >> 2)) * D_ + kc * BK + sg8;
            g2l16(Bhig + go, Bh + h0 * BK);
            g2l16(Blog + go, Bl + h0 * BK);
        }
    };
    auto stageA = [&](int kc, char* buf) {
        f16* Ah = (f16*)(buf);
        f16* Al = (f16*)(buf + 8192);
        if constexpr (PRECONV) {
#pragma unroll
            for (int t = 0; t < 2; ++t) {
                int m0 = w * 32 + t * 16;
                size_t ga = (size_t)(b0 + m0 + (l >> 2)) * D_ + kc * BK + sg8;
                g2l16(hidHi + ga, Ah + m0 * BK);
                g2l16(hidLo + ga, Al + m0 * BK);
            }
        } else {
#pragma unroll
            for (int it = 0; it < 4; ++it) {
                int i  = tid + it * 256;
                int m  = i >> 3;
                int k4 = (i & 7) * 4;
                int ks = ((k4 >> 3) ^ ((m >> 1) & 3)) * 8 + (k4 & 7);
                f32x4 v = *(const f32x4*)(hidden + (size_t)(b0 + m) * D_ + kc * BK + k4);
                f16x4 vh, vl;
#pragma unroll
                for (int j = 0; j < 4; ++j) {
                    f16 hj = (f16)v[j];
                    vh[j] = hj;
                    vl[j] = (f16)(v[j] - (float)hj);
                }
                *(f16x4*)&Ah[m * BK + ks] = vh;
                *(f16x4*)&Al[m * BK + ks] = vl;
            }
        }
    };

    // ---- phase-split chunk compute (T3-lite + T5) ----
    // phase 1: read B frags + A(mi 0,1); MFMA cluster mi 0,1 under setprio.
    // barrier (bounds wave skew -> role diversity for setprio to arbitrate).
    // phase 2: read A(mi 2,3); MFMA cluster mi 2,3 under setprio.
    auto chunk = [&](const char* buf) {
        const f16* Ah = (const f16*)(buf);
        const f16* Al = (const f16*)(buf + 8192);
        const f16* Bh = (const f16*)(buf + 16384);
        const f16* Bl = (const f16*)(buf + 24576);
        f16x8 bh[4], bl[4];
#pragma unroll
        for (int ni = 0; ni < 4; ++ni) {
            int hrow = wn * 64 + ni * 16 + l15;
            bh[ni] = *(const f16x8*)&Bh[hrow * BK + rd8];
            bl[ni] = *(const f16x8*)&Bl[hrow * BK + rd8];
        }
        // phase 1: mi = 0,1
        {
            f16x8 a_h0 = *(const f16x8*)&Ah[(wm * 64 + 0 * 16 + l15) * BK + rd8];
            f16x8 a_l0 = *(const f16x8*)&Al[(wm * 64 + 0 * 16 + l15) * BK + rd8];
            f16x8 a_h1 = *(const f16x8*)&Ah[(wm * 64 + 1 * 16 + l15) * BK + rd8];
            f16x8 a_l1 = *(const f16x8*)&Al[(wm * 64 + 1 * 16 + l15) * BK + rd8];
            __builtin_amdgcn_s_setprio(1);
#pragma unroll
            for (int ni = 0; ni < 4; ++ni) {
                acc[0][ni] = __builtin_amdgcn_mfma_f32_16x16x32_f16(a_l0, bh[ni], acc[0][ni], 0, 0, 0);
                acc[0][ni] = __builtin_amdgcn_mfma_f32_16x16x32_f16(a_h0, bl[ni], acc[0][ni], 0, 0, 0);
                acc[0][ni] = __builtin_amdgcn_mfma_f32_16x16x32_f16(a_h0, bh[ni], acc[0][ni], 0, 0, 0);
            }
#pragma unroll
            for (int ni = 0; ni < 4; ++ni) {
                acc[1][ni] = __builtin_amdgcn_mfma_f32_16x16x32_f16(a_l1, bh[ni], acc[1][ni], 0, 0, 0);
                acc[1][ni] = __builtin_amdgcn_mfma_f32_16x16x32_f16(a_h1, bl[ni], acc[1][ni], 0, 0, 0);
                acc[1][ni] = __builtin_amdgcn_mfma_f32_16x16x32_f16(a_h1, bh[ni], acc[1][ni], 0, 0, 0);
            }
            __builtin_amdgcn_s_setprio(0);
        }
        __builtin_amdgcn_s_barrier();
        // phase 2: mi = 2,3
        {
            f16x8 a_h2 = *(const f16x8*)&Ah[(wm * 64 + 2 * 16 + l15) * BK + rd8];
            f16x8 a_l2 = *(const f16x8*)&Al[(wm * 64 + 2 * 16 + l15) * BK + rd8];
            f16x8 a_h3 = *(const f16x8*)&Ah[(wm * 64 + 3 * 16 + l15) * BK + rd8];
            f16x8 a_l3 = *(const f16x8*)&Al[(wm * 64 + 3 * 16 + l15) * BK + rd8];
            __builtin_amdgcn_s_setprio(1);
#pragma unroll
            for (int ni = 0; ni < 4; ++ni) {
                acc[2][ni] = __builtin_amdgcn_mfma_f32_16x16x32_f16(a_l2, bh[ni], acc[2][ni], 0, 0, 0);
                acc[2][ni] = __builtin_amdgcn_mfma_f32_16x16x32_f16(a_h2, bl[ni], acc[2][ni], 0, 0, 0);
                acc[2][ni] = __builtin_amdgcn_mfma_f32_16x16x32_f16(a_h2, bh[ni], acc[2][ni], 0, 0, 0);
            }
#pragma unroll
            for (int ni = 0; ni < 4; ++ni) {
                acc[3][ni] = __builtin_amdgcn_mfma_f32_16x16x32_f16(a_l3, bh[ni], acc[3][ni], 0, 0, 0);
                acc[3][ni] = __builtin_amdgcn_mfma_f32_16x16x32_f16(a_h3, bl[ni], acc[3][ni], 0, 0, 0);
                acc[3][ni] = __builtin_amdgcn_mfma_f32_16x16x32_f16(a_h3, bh[ni], acc[3][ni], 0, 0, 0);
            }
            __builtin_amdgcn_s_setprio(0);
        }
    };

    char* buf0 = smem;
    char* buf1 = smem + 32768;

    // ---- 2-buf pipeline, counted vmcnt (never 0 in loop), phase-split chunks ----
    stageA(0, buf0);
    stageB(0, buf0);
    asm volatile("s_waitcnt vmcnt(0)" ::: "memory");
    __builtin_amdgcn_s_barrier();
    for (int kc = 0; kc < 16; kc += 2) {
        // even chunk: cur=buf0
        stageA(kc + 1, buf1);
        stageB(kc + 1, buf1);
        asm volatile("s_waitcnt vmcnt(8)" ::: "memory");
        __builtin_amdgcn_s_barrier();
        chunk(buf0);
        __builtin_amdgcn_s_barrier();
        // odd chunk: cur=buf1
        if (kc + 2 < 16) {
            stageA(kc + 2, buf0);
            stageB(kc + 2, buf0);
            asm volatile("s_waitcnt vmcnt(8)" ::: "memory");
        } else {
            asm volatile("s_waitcnt vmcnt(0)" ::: "memory");
        }
        __builtin_amdgcn_s_barrier();
        chunk(buf1);
        __builtin_amdgcn_s_barrier();
    }

    // ---- epilogue: bias + exact gelu + GEMM2 via 16-lane butterfly ----
    float b1v[4];
#pragma unroll
    for (int ni = 0; ni < 4; ++ni)
        b1v[ni] = b1[p * H_ + wn * 64 + ni * 16 + l15];

#pragma unroll
    for (int mi = 0; mi < 4; ++mi) {
        float po[4][4];
#pragma unroll
        for (int r = 0; r < 4; ++r)
#pragma unroll
            for (int o = 0; o < 4; ++o) po[r][o] = 0.0f;

#pragma unroll
        for (int ni = 0; ni < 4; ++ni) {
            int h = wn * 64 + ni * 16 + l15;
            f32x4 w4 = ((const f32x4*)W2s)[h];
#pragma unroll
            for (int r = 0; r < 4; ++r) {
                float gg = gelu_exact(acc[mi][ni][r] + b1v[ni]);
#pragma unroll
                for (int o = 0; o < 4; ++o) po[r][o] = fmaf(gg, w4[o], po[r][o]);
            }
        }
#pragma unroll
        for (int off = 1; off < 16; off <<= 1) {
#pragma unroll
            for (int r = 0; r < 4; ++r)
#pragma unroll
                for (int o = 0; o < 4; ++o)
                    po[r][o] += __shfl_xor(po[r][o], off, 64);
        }
        float v = po[0][0];
#pragma unroll
        for (int rr = 0; rr < 4; ++rr)
#pragma unroll
            for (int oo = 0; oo < 4; ++oo)
                if (l15 == rr * 4 + oo) v = po[rr][oo];
        red[(wn * 128 + wm * 64 + mi * 16 + l4 * 4 + (l15 >> 2)) * 4 + (l15 & 3)] = v;
    }
    __syncthreads();

    if (tid < BM) {
        int b = b0 + tid;
        const float* r0p = &red[(0 * 128 + tid) * 4];
        const float* r1p = &red[(1 * 128 + tid) * 4];
        float o0 = r0p[0] + r1p[0] + b2[p * 4 + 0];
        float o1 = r0p[1] + r1p[1] + b2[p * 4 + 1];
        float o2 = r0p[2] + r1p[2] + b2[p * 4 + 2];
        float o3 = r0p[3] + r1p[3] + b2[p * 4 + 3];
        *reinterpret_cast<float4*>(out_ops + ((size_t)p * B + b) * MAXO) =
            make_float4(o0, o1, o2, o3);

        if (pids[b] == p) {
            float a0 = rintf(o0), a1 = rintf(o1), a2 = rintf(o2), a3 = rintf(o3);
            float r0 = 0.0f, r1 = 0.0f, r2 = 0.0f;
            switch (p) {
                case 0: r0 = a0 + a1; break;
                case 1: r0 = a0 - a1; break;
                case 2: r0 = a0 * a1; break;
                case 3: {
                    float bs = (a1 == 0.0f) ? 1.0f : a1;
                    float m = fmodf(a0, bs);
                    if (m != 0.0f && ((m < 0.0f) != (bs < 0.0f))) m += bs;
                    r0 = m;
                } break;
                case 4: {
                    float bs = (a1 == 0.0f) ? 1.0f : a1;
                    r0 = floorf(a0 / bs);
                } break;
                case 5: { float tt = a0 * 60.0f + a1 + a2 * 60.0f + a3; time_decomp(tt, r0, r1, r2); } break;
                case 6: { float tt = a0 * 60.0f + a1 - (a2 * 60.0f + a3); time_decomp(tt, r0, r1, r2); } break;
                case 7: { float tt = fabsf(a0 * 60.0f + a1 - (a2 * 60.0f + a3)); time_decomp(tt, r0, r1, r2); } break;
                case 8: r0 = (a0 > a1) ? 1.0f : 0.0f; break;
                case 9: r0 = (a0 == a1) ? 1.0f : 0.0f; break;
            }
            size_t ob = (size_t)b * 3;
            out_results[ob + 0] = r0;
            out_results[ob + 1] = r1;
            out_results[ob + 2] = r2;
        }
    }
}

extern "C" void kernel_launch(void* const* d_in, const int* in_sizes, int n_in,
                              void* d_out, int out_size, void* d_ws, size_t ws_size,
                              hipStream_t stream) {
    const float* hidden = (const float*)d_in[0];
    const int*   pids   = (const int*)  d_in[1];
    const float* Wr     = (const float*)d_in[2];
    const float* br     = (const float*)d_in[3];
    const float* W1     = (const float*)d_in[4];
    const float* b1     = (const float*)d_in[5];
    const float* W2     = (const float*)d_in[6];
    const float* b2     = (const float*)d_in[7];

    const int B = in_sizes[1];

    float* out         = (float*)d_out;
    float* out_results = out;                                          // [B,3]
    float* out_router  = out + (size_t)B * 3;                          // [B,10]
    float* out_ops     = out + (size_t)B * 13;                         // [P,B,4]
    float* out_pids    = out + (size_t)B * 13 + (size_t)P_ * B * MAXO; // [B]

    const size_t nW1  = (size_t)P_ * H_ * D_;
    const size_t nHid = (size_t)B * D_;
    const size_t need = (2 * nW1 + 2 * nHid) * sizeof(f16);

    f16* W1Thi = (f16*)d_ws;
    f16* W1Tlo = W1Thi + nW1;

    cvt_w1_kernel<<<(int)(nW1 / 256), 256, 0, stream>>>(W1, W1Thi, W1Tlo);

    if (ws_size >= need) {
        f16* hidHi = W1Tlo + nW1;
        f16* hidLo = hidHi + nHid;
        router_cvt_kernel<true><<<B / 4, 256, 0, stream>>>(
            hidden, Wr, br, pids, out_router, out_pids, hidHi, hidLo, B);
        extractor_kernel<true><<<(B / BM) * P_, 256, 0, stream>>>(
            hidden, hidHi, hidLo, pids, W1Thi, W1Tlo, b1, W2, b2,
            out_results, out_ops, B);
    } else {
        router_cvt_kernel<false><<<B / 4, 256, 0, stream>>>(
            hidden, Wr, br, pids, out_router, out_pids, nullptr, nullptr, B);
        extractor_kernel<false><<<(B / BM) * P_, 256, 0, stream>>>(
            hidden, nullptr, nullptr, pids, W1Thi, W1Tlo, b1, W2, b2,
            out_results, out_ops, B);
    }
}

// Round 11
// 758.409 us; speedup vs baseline: 1.2622x; 1.0292x over previous
//
#include <hip/hip_runtime.h>
#include <math.h>

constexpr int D_   = 512;   // d_model
constexpr int H_   = 128;   // extractor hidden
constexpr int P_   = 10;    // n_programs
constexpr int MAXO = 4;
constexpr int BM   = 128;   // token tile
constexpr int BK   = 32;    // K chunk (= one MFMA K step)

typedef _Float16 f16;
typedef f16 f16x4 __attribute__((ext_vector_type(4)));
typedef f16 f16x8 __attribute__((ext_vector_type(8)));
typedef float f32x4 __attribute__((ext_vector_type(4)));

__device__ __forceinline__ float gelu_exact(float x) {
    return 0.5f * x * (1.0f + erff(x * 0.70710678118654752f));
}

__device__ __forceinline__ void time_decomp(float t, float& hr, float& mi, float& dy) {
    float days = floorf(t / 1440.0f);
    float rem  = t - days * 1440.0f;
    float hours = floorf(rem / 60.0f);
    float minutes = rem - hours * 60.0f;
    hr = hours; mi = minutes; dy = days;
}

__device__ __forceinline__ void g2l16(const f16* g, f16* l) {
    __builtin_amdgcn_global_load_lds(
        (const __attribute__((address_space(1))) void*)g,
        (__attribute__((address_space(3))) void*)l, 16, 0, 0);
}

// W1 [P][D][H] f32 -> W1T_hi / W1T_lo [P][H][D] f16 (transposed + split)
__global__ __launch_bounds__(256) void cvt_w1_kernel(
    const float* __restrict__ W1, f16* __restrict__ hi, f16* __restrict__ lo)
{
    int i = blockIdx.x * 256 + threadIdx.x;
    float x = W1[i];
    f16 h = (f16)x;
    f16 L = (f16)(x - (float)h);
    int dh = i % (D_ * H_);
    int p  = i / (D_ * H_);
    int d  = dh / H_;
    int hh = dh % H_;
    size_t o = ((size_t)(p * H_ + hh)) * D_ + d;
    hi[o] = h; lo[o] = L;
}

// Fused: router logits + program_ids-as-float + hidden f32 -> f16 hi/lo split.
template <bool WRITE_SPLIT>
__global__ __launch_bounds__(256) void router_cvt_kernel(
    const float* __restrict__ hidden, const float* __restrict__ Wr,
    const float* __restrict__ br, const int* __restrict__ pids,
    float* __restrict__ out_router, float* __restrict__ out_pids,
    f16* __restrict__ hidHi, f16* __restrict__ hidLo, int B)
{
    __shared__ float Wrs[D_ * 12];
    const int tid = threadIdx.x;
    for (int i = tid; i < D_ * P_; i += 256) {
        int k = i / P_;
        int q = i - k * P_;
        Wrs[k * 12 + q] = Wr[i];
    }
    __syncthreads();

    const int lane = tid & 63;
    const int wv   = tid >> 6;
    const int b    = blockIdx.x * 4 + wv;
    const float* hrow = hidden + (size_t)b * D_;

    float acc[P_];
#pragma unroll
    for (int q = 0; q < P_; ++q) acc[q] = 0.0f;

#pragma unroll
    for (int j = 0; j < 8; ++j) {
        int k = j * 64 + lane;
        float hv = hrow[k];
        if (WRITE_SPLIT) {
            f16 hh = (f16)hv;
            hidHi[(size_t)b * D_ + k] = hh;
            hidLo[(size_t)b * D_ + k] = (f16)(hv - (float)hh);
        }
        float wv12[12];
        *reinterpret_cast<float4*>(&wv12[0]) = *reinterpret_cast<const float4*>(&Wrs[k * 12 + 0]);
        *reinterpret_cast<float4*>(&wv12[4]) = *reinterpret_cast<const float4*>(&Wrs[k * 12 + 4]);
        *reinterpret_cast<float2*>(&wv12[8]) = *reinterpret_cast<const float2*>(&Wrs[k * 12 + 8]);
#pragma unroll
        for (int q = 0; q < P_; ++q) acc[q] = fmaf(hv, wv12[q], acc[q]);
    }

#pragma unroll
    for (int off = 1; off < 64; off <<= 1) {
#pragma unroll
        for (int q = 0; q < P_; ++q)
            acc[q] += __shfl_xor(acc[q], off, 64);
    }

    if (lane == 0) {
        float* o = out_router + (size_t)b * P_;
#pragma unroll
        for (int q = 0; q < P_; ++q) o[q] = acc[q] + br[q];
        out_pids[b] = (float)pids[b];
    }
}

template <bool PRECONV>
__global__ __launch_bounds__(512, 2) void extractor_kernel(
    const float* __restrict__ hidden,   // [B, D] f32
    const f16*   __restrict__ hidHi,    // [B, D] (PRECONV only)
    const f16*   __restrict__ hidLo,    // [B, D]
    const int*   __restrict__ pids,     // [B]
    const f16*   __restrict__ W1Thi,    // [P][H][D]
    const f16*   __restrict__ W1Tlo,    // [P][H][D]
    const float* __restrict__ b1,       // [P, H]
    const float* __restrict__ W2,       // [P, H, MAXO]
    const float* __restrict__ b2,       // [P, MAXO]
    float* __restrict__ out_results,    // [B, 3]
    float* __restrict__ out_ops,        // [P, B, MAXO]
    int B)
{
    // LDS: buf0 {Ah,Al,Bh,Bl} 32K | buf1 32K | red 4K | W2s 2K = 71680
    __shared__ __align__(16) char smem[71680];
    float* red = (float*)(smem + 65536);   // [2][128][4]
    float* W2s = (float*)(smem + 69632);   // [128][4]

    const int bid = blockIdx.x;
    const int ngroups = gridDim.x / P_;
    int g, p;
    if ((ngroups & 7) == 0) {
        // XCD-aware: hw xcd = bid % 8; each XCD gets contiguous (tile, program)
        // groups so a tile's 10 program-blocks share one L2.
        const int gpx = ngroups >> 3;
        const int x   = bid & 7;
        const int q   = bid >> 3;
        g = x * gpx + q / P_;
        p = q % P_;
    } else {
        g = bid / P_;
        p = bid % P_;
    }
    const int b0  = g * BM;
    const int tid = threadIdx.x;
    const int l   = tid & 63;
    const int w   = tid >> 6;          // 8 waves
    const int wm  = w >> 1, wn = w & 1; // wave tile: 32 tok x 64 h
    const int l15 = l & 15, l4 = l >> 4;

    // ---- swizzle (both-sides, involution; rule #21; proven 0-conflict) ----
    const int sg8 = (((l & 3) ^ ((l >> 3) & 3))) * 8;     // stage-side, f16 units
    const int rd8 = ((l4 ^ ((l15 >> 1) & 3))) * 8;        // read-side, f16 units

    if (tid < H_) {
        ((f32x4*)W2s)[tid] = ((const f32x4*)(W2 + (size_t)p * H_ * 4))[tid];
    }

    f32x4 acc[2][4];
#pragma unroll
    for (int mi = 0; mi < 2; ++mi)
#pragma unroll
        for (int ni = 0; ni < 4; ++ni) acc[mi][ni] = (f32x4){0.f, 0.f, 0.f, 0.f};

    const f16* Bhig = W1Thi + (size_t)p * H_ * D_;
    const f16* Blog = W1Tlo + (size_t)p * H_ * D_;

    // per chunk per wave: 4 g2l loads (Bh, Bl, Ah, Al — 1KB each, wave-uniform base)
    auto stage = [&](int kc, char* buf) {
        f16* Ah = (f16*)(buf);
        f16* Al = (f16*)(buf + 8192);
        f16* Bh = (f16*)(buf + 16384);
        f16* Bl = (f16*)(buf + 24576);
        const int r0 = w * 16;                           // 16-row unit per wave
        size_t gb = (size_t)(r0 + (l >> 2)) * D_ + kc * BK + sg8;
        g2l16(Bhig + gb, Bh + r0 * BK);
        g2l16(Blog + gb, Bl + r0 * BK);
        if constexpr (PRECONV) {
            size_t ga = (size_t)(b0 + r0 + (l >> 2)) * D_ + kc * BK + sg8;
            g2l16(hidHi + ga, Ah + r0 * BK);
            g2l16(hidLo + ga, Al + r0 * BK);
        } else {
#pragma unroll
            for (int it = 0; it < 2; ++it) {
                int i  = tid + it * 512;
                int m  = i >> 3;
                int k4 = (i & 7) * 4;
                int ks = ((k4 >> 3) ^ ((m >> 1) & 3)) * 8 + (k4 & 7);
                f32x4 v = *(const f32x4*)(hidden + (size_t)(b0 + m) * D_ + kc * BK + k4);
                f16x4 vh, vl;
#pragma unroll
                for (int j = 0; j < 4; ++j) {
                    f16 hj = (f16)v[j];
                    vh[j] = hj;
                    vl[j] = (f16)(v[j] - (float)hj);
                }
                *(f16x4*)&Ah[m * BK + ks] = vh;
                *(f16x4*)&Al[m * BK + ks] = vl;
            }
        }
    };

    auto compute = [&](const char* buf) {
        const f16* Ah = (const f16*)(buf);
        const f16* Al = (const f16*)(buf + 8192);
        const f16* Bh = (const f16*)(buf + 16384);
        const f16* Bl = (const f16*)(buf + 24576);
        f16x8 bh[4], bl[4];
#pragma unroll
        for (int ni = 0; ni < 4; ++ni) {
            int hrow = wn * 64 + ni * 16 + l15;
            bh[ni] = *(const f16x8*)&Bh[hrow * BK + rd8];
            bl[ni] = *(const f16x8*)&Bl[hrow * BK + rd8];
        }
#pragma unroll
        for (int mi = 0; mi < 2; ++mi) {
            int mrow = wm * 32 + mi * 16 + l15;
            f16x8 a_h = *(const f16x8*)&Ah[mrow * BK + rd8];
            f16x8 a_l = *(const f16x8*)&Al[mrow * BK + rd8];
#pragma unroll
            for (int ni = 0; ni < 4; ++ni) {
                acc[mi][ni] = __builtin_amdgcn_mfma_f32_16x16x32_f16(a_l, bh[ni], acc[mi][ni], 0, 0, 0);
                acc[mi][ni] = __builtin_amdgcn_mfma_f32_16x16x32_f16(a_h, bl[ni], acc[mi][ni], 0, 0, 0);
                acc[mi][ni] = __builtin_amdgcn_mfma_f32_16x16x32_f16(a_h, bh[ni], acc[mi][ni], 0, 0, 0);
            }
        }
    };

    char* buf0 = smem;
    char* buf1 = smem + 32768;

    // ---- 2-buf pipeline, counted vmcnt (never 0 in loop): 4 loads/wave/chunk ----
    stage(0, buf0);
    asm volatile("s_waitcnt vmcnt(0)" ::: "memory");
    __builtin_amdgcn_s_barrier();
    for (int kc = 0; kc < 16; kc += 2) {
        // even chunk: cur=buf0
        stage(kc + 1, buf1);
        asm volatile("s_waitcnt vmcnt(4)" ::: "memory");
        __builtin_amdgcn_s_barrier();
        compute(buf0);
        __builtin_amdgcn_s_barrier();
        // odd chunk: cur=buf1
        if (kc + 2 < 16) {
            stage(kc + 2, buf0);
            asm volatile("s_waitcnt vmcnt(4)" ::: "memory");
        } else {
            asm volatile("s_waitcnt vmcnt(0)" ::: "memory");
        }
        __builtin_amdgcn_s_barrier();
        compute(buf1);
        __builtin_amdgcn_s_barrier();
    }

    // ---- epilogue: bias + exact gelu + GEMM2 via 16-lane butterfly ----
    float b1v[4];
#pragma unroll
    for (int ni = 0; ni < 4; ++ni)
        b1v[ni] = b1[p * H_ + wn * 64 + ni * 16 + l15];

#pragma unroll
    for (int mi = 0; mi < 2; ++mi) {
        float po[4][4];
#pragma unroll
        for (int r = 0; r < 4; ++r)
#pragma unroll
            for (int o = 0; o < 4; ++o) po[r][o] = 0.0f;

#pragma unroll
        for (int ni = 0; ni < 4; ++ni) {
            int h = wn * 64 + ni * 16 + l15;
            f32x4 w4 = ((const f32x4*)W2s)[h];
#pragma unroll
            for (int r = 0; r < 4; ++r) {
                float gg = gelu_exact(acc[mi][ni][r] + b1v[ni]);
#pragma unroll
                for (int o = 0; o < 4; ++o) po[r][o] = fmaf(gg, w4[o], po[r][o]);
            }
        }
#pragma unroll
        for (int off = 1; off < 16; off <<= 1) {
#pragma unroll
            for (int r = 0; r < 4; ++r)
#pragma unroll
                for (int o = 0; o < 4; ++o)
                    po[r][o] += __shfl_xor(po[r][o], off, 64);
        }
        float v = po[0][0];
#pragma unroll
        for (int rr = 0; rr < 4; ++rr)
#pragma unroll
            for (int oo = 0; oo < 4; ++oo)
                if (l15 == rr * 4 + oo) v = po[rr][oo];
        red[(wn * 128 + wm * 32 + mi * 16 + l4 * 4 + (l15 >> 2)) * 4 + (l15 & 3)] = v;
    }
    __syncthreads();

    if (tid < BM) {
        int b = b0 + tid;
        const float* r0p = &red[(0 * 128 + tid) * 4];
        const float* r1p = &red[(1 * 128 + tid) * 4];
        float o0 = r0p[0] + r1p[0] + b2[p * 4 + 0];
        float o1 = r0p[1] + r1p[1] + b2[p * 4 + 1];
        float o2 = r0p[2] + r1p[2] + b2[p * 4 + 2];
        float o3 = r0p[3] + r1p[3] + b2[p * 4 + 3];
        *reinterpret_cast<float4*>(out_ops + ((size_t)p * B + b) * MAXO) =
            make_float4(o0, o1, o2, o3);

        if (pids[b] == p) {
            float a0 = rintf(o0), a1 = rintf(o1), a2 = rintf(o2), a3 = rintf(o3);
            float r0 = 0.0f, r1 = 0.0f, r2 = 0.0f;
            switch (p) {
                case 0: r0 = a0 + a1; break;
                case 1: r0 = a0 - a1; break;
                case 2: r0 = a0 * a1; break;
                case 3: {
                    float bs = (a1 == 0.0f) ? 1.0f : a1;
                    float m = fmodf(a0, bs);
                    if (m != 0.0f && ((m < 0.0f) != (bs < 0.0f))) m += bs;
                    r0 = m;
                } break;
                case 4: {
                    float bs = (a1 == 0.0f) ? 1.0f : a1;
                    r0 = floorf(a0 / bs);
                } break;
                case 5: { float tt = a0 * 60.0f + a1 + a2 * 60.0f + a3; time_decomp(tt, r0, r1, r2); } break;
                case 6: { float tt = a0 * 60.0f + a1 - (a2 * 60.0f + a3); time_decomp(tt, r0, r1, r2); } break;
                case 7: { float tt = fabsf(a0 * 60.0f + a1 - (a2 * 60.0f + a3)); time_decomp(tt, r0, r1, r2); } break;
                case 8: r0 = (a0 > a1) ? 1.0f : 0.0f; break;
                case 9: r0 = (a0 == a1) ? 1.0f : 0.0f; break;
            }
            size_t ob = (size_t)b * 3;
            out_results[ob + 0] = r0;
            out_results[ob + 1] = r1;
            out_results[ob + 2] = r2;
        }
    }
}

extern "C" void kernel_launch(void* const* d_in, const int* in_sizes, int n_in,
                              void* d_out, int out_size, void* d_ws, size_t ws_size,
                              hipStream_t stream) {
    const float* hidden = (const float*)d_in[0];
    const int*   pids   = (const int*)  d_in[1];
    const float* Wr     = (const float*)d_in[2];
    const float* br     = (const float*)d_in[3];
    const float* W1     = (const float*)d_in[4];
    const float* b1     = (const float*)d_in[5];
    const float* W2     = (const float*)d_in[6];
    const float* b2     = (const float*)d_in[7];

    const int B = in_sizes[1];

    float* out         = (float*)d_out;
    float* out_results = out;                                          // [B,3]
    float* out_router  = out + (size_t)B * 3;                          // [B,10]
    float* out_ops     = out + (size_t)B * 13;                         // [P,B,4]
    float* out_pids    = out + (size_t)B * 13 + (size_t)P_ * B * MAXO; // [B]

    const size_t nW1  = (size_t)P_ * H_ * D_;
    const size_t nHid = (size_t)B * D_;
    const size_t need = (2 * nW1 + 2 * nHid) * sizeof(f16);

    f16* W1Thi = (f16*)d_ws;
    f16* W1Tlo = W1Thi + nW1;

    cvt_w1_kernel<<<(int)(nW1 / 256), 256, 0, stream>>>(W1, W1Thi, W1Tlo);

    if (ws_size >= need) {
        f16* hidHi = W1Tlo + nW1;
        f16* hidLo = hidHi + nHid;
        router_cvt_kernel<true><<<B / 4, 256, 0, stream>>>(
            hidden, Wr, br, pids, out_router, out_pids, hidHi, hidLo, B);
        extractor_kernel<true><<<(B / BM) * P_, 512, 0, stream>>>(
            hidden, hidHi, hidLo, pids, W1Thi, W1Tlo, b1, W2, b2,
            out_results, out_ops, B);
    } else {
        router_cvt_kernel<false><<<B / 4, 256, 0, stream>>>(
            hidden, Wr, br, pids, out_router, out_pids, nullptr, nullptr, B);
        extractor_kernel<false><<<(B / BM) * P_, 512, 0, stream>>>(
            hidden, nullptr, nullptr, pids, W1Thi, W1Tlo, b1, W2, b2,
            out_results, out_ops, B);
    }
}